// Round 6
// baseline (933.403 us; speedup 1.0000x reference)
//
#include <hip/hip_runtime.h>
#include <math.h>

#define BB 1024
#define TT 512

__device__ __forceinline__ float fast_rcp(float x){ return __builtin_amdgcn_rcpf(x); }
__device__ __forceinline__ float sigmoidf_(float x){ return fast_rcp(1.0f + __expf(-x)); }
__device__ __forceinline__ float tanhf_(float x){
    float t = __expf(2.0f * x);
    return 1.0f - 2.0f * fast_rcp(t + 1.0f);
}

// Volatile read: the load may execute exactly once -> the compiler cannot
// rematerialize/sink it into the t-loop; the value must stay register-resident.
__device__ __forceinline__ float vload(const float* p){
    return *(const volatile float*)p;
}
__device__ __forceinline__ float4 vload4(const float* p){
    float4 r;
    r.x = vload(p+0); r.y = vload(p+1); r.z = vload(p+2); r.w = vload(p+3);
    return r;
}

// Layer 0 bidirectional GRU. Block = 1 wave = one (batch, direction) sequence.
// lane = i + 32*half: i = h-element, half = k-split half of the recurrent dot.
__global__ __attribute__((amdgpu_flat_work_group_size(64,64)))
__attribute__((amdgpu_waves_per_eu(2,2))) void gru_l0(
    const float* __restrict__ x,      // (B,T,4)
    const float* __restrict__ w_ih,   // (2,96,4)
    const float* __restrict__ w_hh,   // (2,96,32)
    const float* __restrict__ b_ih,   // (2,96)
    const float* __restrict__ b_hh,   // (2,96)
    float* __restrict__ h1)           // (B,T,64)
{
    const int b    = blockIdx.x >> 1;
    const int d    = blockIdx.x & 1;
    const int lane = threadIdx.x;
    const int i    = lane & 31;
    const int half = lane >> 5;

    float4 wi[3];        // full input row (4), redundant across halves
    float4 wh[3][4];     // recurrent row, j-range [half*16, half*16+16)
    float  bx[3];        // g=0,1: b_ih+b_hh ; g=2: b_ih only
    float  bhn;          // b_hh for n gate (stays inside r*(...))
    #pragma unroll
    for (int g = 0; g < 3; ++g) {
        const int row = d*96 + g*32 + i;
        wi[g] = vload4(w_ih + (size_t)row*4);
        #pragma unroll
        for (int k = 0; k < 4; ++k)
            wh[g][k] = vload4(w_hh + (size_t)row*32 + half*16 + k*4);
        bx[g] = (g < 2) ? (vload(b_ih + row) + vload(b_hh + row)) : vload(b_ih + row);
    }
    bhn = vload(b_hh + d*96 + 2*32 + i);

    __shared__ __align__(16) float h_sh[32];
    if (!half) h_sh[i] = 0.0f;
    float h = 0.0f;

    const size_t xbase = (size_t)b * TT;
    float4 xc = *(const float4*)(x + (xbase + (d ? TT-1 : 0))*4);

    for (int t = 0; t < TT; ++t) {
        const int tx = d ? (TT-1-t) : t;
        float4 xn4 = xc;
        if (t+1 < TT) {
            const int tx1 = d ? (TT-2-t) : (t+1);
            xn4 = *(const float4*)(x + (xbase + tx1)*4);
        }
        float xg[3], hg[3];
        #pragma unroll
        for (int g = 0; g < 3; ++g) {
            xg[g] = bx[g] + xc.x*wi[g].x + xc.y*wi[g].y + xc.z*wi[g].z + xc.w*wi[g].w;
            hg[g] = 0.0f;
        }
        #pragma unroll
        for (int k = 0; k < 4; ++k) {
            const float4 hv = *(const float4*)&h_sh[half*16 + k*4];  // per-half broadcast
            #pragma unroll
            for (int g = 0; g < 3; ++g)
                hg[g] += hv.x*wh[g][k].x + hv.y*wh[g][k].y + hv.z*wh[g][k].z + hv.w*wh[g][k].w;
        }
        #pragma unroll
        for (int g = 0; g < 3; ++g) hg[g] += __shfl_xor(hg[g], 32, 64);
        const float r = sigmoidf_(xg[0] + hg[0]);
        const float z = sigmoidf_(xg[1] + hg[1]);
        const float n = tanhf_(xg[2] + r*(hg[2] + bhn));
        h = n + z*(h - n);
        if (!half) {
            h_sh[i] = h;
            h1[(xbase + tx)*64 + d*32 + i] = h;
        }
        xc = xn4;
    }
}

// Layer 1 bidirectional GRU, input width 64. Same wave layout; projection
// k-split too (wi: 96 VGPR, wh: 48 VGPR). Weights loaded via volatile so the
// compiler cannot sink the loads into the t-loop (R4/R5: VGPR=104/92, loads
// re-fetched every step -> latency-chain bound).
__global__ __attribute__((amdgpu_flat_work_group_size(64,64)))
__attribute__((amdgpu_waves_per_eu(2,2))) void gru_l1(
    const float* __restrict__ h1,     // (B,T,64)
    const float* __restrict__ w_ih,   // (2,96,64)
    const float* __restrict__ w_hh,   // (2,96,32)
    const float* __restrict__ b_ih,   // (2,96)
    const float* __restrict__ b_hh,   // (2,96)
    float* __restrict__ out2)         // (B,T,64)
{
    const int b    = blockIdx.x >> 1;
    const int d    = blockIdx.x & 1;
    const int lane = threadIdx.x;
    const int i    = lane & 31;
    const int half = lane >> 5;

    float4 wi[3][8];     // proj row, k-range [half*32, half*32+32)
    float4 wh[3][4];     // rec row, j-range [half*16, half*16+16)
    float  bx[3];
    float  bhn;
    #pragma unroll
    for (int g = 0; g < 3; ++g) {
        const size_t row = (size_t)(d*96 + g*32 + i);
        #pragma unroll
        for (int k = 0; k < 8; ++k)
            wi[g][k] = vload4(w_ih + row*64 + half*32 + k*4);
        #pragma unroll
        for (int k = 0; k < 4; ++k)
            wh[g][k] = vload4(w_hh + row*32 + half*16 + k*4);
        bx[g] = (g < 2) ? (vload(b_ih + row) + vload(b_hh + row)) : vload(b_ih + row);
    }
    bhn = vload(b_hh + d*96 + 2*32 + i);

    __shared__ __align__(16) float h_sh[32];
    __shared__ __align__(16) float xbuf[2][64];
    if (!half) h_sh[i] = 0.0f;
    float h = 0.0f;

    const size_t base = (size_t)b * TT;

    // stage row 0; prefetch row 1 (1 float per lane, coalesced 256B)
    float c1;
    {
        const int r0 = d ? (TT-1) : 0;
        xbuf[0][lane] = h1[(base + r0)*64 + lane];
        const int r1 = d ? (TT-2) : 1;
        c1 = h1[(base + r1)*64 + lane];
    }

    int buf = 0;
    for (int t = 0; t < TT; ++t) {
        // prefetch row t+2 (2 steps of latency cover)
        float c2 = c1;
        if (t+2 < TT) {
            const int r2 = d ? (TT-3-t) : (t+2);
            c2 = h1[(base + r2)*64 + lane];
        }
        // projection from staged row (independent of h -> hides h LDS round trip)
        float xg[3], hg[3];
        #pragma unroll
        for (int g = 0; g < 3; ++g) { xg[g] = bx[g]; hg[g] = 0.0f; }
        #pragma unroll
        for (int k = 0; k < 8; ++k) {
            const float4 xv = *(const float4*)&xbuf[buf][half*32 + k*4];  // broadcast
            #pragma unroll
            for (int g = 0; g < 3; ++g)
                xg[g] += xv.x*wi[g][k].x + xv.y*wi[g][k].y + xv.z*wi[g][k].z + xv.w*wi[g][k].w;
        }
        // stage row t+1 into the other buffer (c1 ready from last iter's prefetch)
        if (t+1 < TT) xbuf[buf^1][lane] = c1;
        // recurrent part
        #pragma unroll
        for (int k = 0; k < 4; ++k) {
            const float4 hv = *(const float4*)&h_sh[half*16 + k*4];       // broadcast
            #pragma unroll
            for (int g = 0; g < 3; ++g)
                hg[g] += hv.x*wh[g][k].x + hv.y*wh[g][k].y + hv.z*wh[g][k].z + hv.w*wh[g][k].w;
        }
        #pragma unroll
        for (int g = 0; g < 3; ++g) hg[g] += __shfl_xor(hg[g], 32, 64);
        const float r = sigmoidf_(xg[0] + hg[0]);
        const float z = sigmoidf_(xg[1] + hg[1]);
        const float n = tanhf_(xg[2] + r*(hg[2] + bhn));
        h = n + z*(h - n);
        if (!half) {
            h_sh[i] = h;
            const int tx = d ? (TT-1-t) : t;
            out2[(base + tx)*64 + d*32 + i] = h;
        }
        c1 = c2;
        buf ^= 1;
    }
}

// Attention pooling + FC + sigmoid. One block per batch element.
__global__ __launch_bounds__(256) void attn_fc(
    const float* __restrict__ out2,   // (B,T,64)
    const float* __restrict__ attn_w, // (64)
    const float* __restrict__ attn_b, // (1)
    const float* __restrict__ fc_w,   // (64)
    const float* __restrict__ fc_b,   // (1)
    float* __restrict__ out)          // (B,1)
{
    const int b    = blockIdx.x;
    const int tid  = threadIdx.x;
    const int wave = tid >> 6;
    const int lane = tid & 63;

    __shared__ float logit_sh[TT];
    __shared__ float red_sh[4];
    __shared__ float ctx_sh[4][64];

    const float aw = attn_w[lane];
    const float ab = attn_b[0];

    for (int t = wave; t < TT; t += 4) {
        float v = out2[((size_t)b*TT + t)*64 + lane] * aw;
        #pragma unroll
        for (int off = 32; off > 0; off >>= 1) v += __shfl_xor(v, off, 64);
        if (lane == 0) logit_sh[t] = v + ab;
    }
    __syncthreads();

    float m = -INFINITY;
    for (int t = tid; t < TT; t += 256) m = fmaxf(m, logit_sh[t]);
    #pragma unroll
    for (int off = 32; off > 0; off >>= 1) m = fmaxf(m, __shfl_xor(m, off, 64));
    if (lane == 0) red_sh[wave] = m;
    __syncthreads();
    m = fmaxf(fmaxf(red_sh[0], red_sh[1]), fmaxf(red_sh[2], red_sh[3]));
    __syncthreads();
    float s = 0.0f;
    for (int t = tid; t < TT; t += 256) {
        const float e = __expf(logit_sh[t] - m);
        logit_sh[t] = e;
        s += e;
    }
    #pragma unroll
    for (int off = 32; off > 0; off >>= 1) s += __shfl_xor(s, off, 64);
    if (lane == 0) red_sh[wave] = s;
    __syncthreads();
    s = red_sh[0] + red_sh[1] + red_sh[2] + red_sh[3];
    const float inv_s = 1.0f / s;

    float acc = 0.0f;
    for (int t = wave; t < TT; t += 4)
        acc += logit_sh[t] * out2[((size_t)b*TT + t)*64 + lane];
    ctx_sh[wave][lane] = acc;
    __syncthreads();
    if (wave == 0) {
        const float c = (ctx_sh[0][lane] + ctx_sh[1][lane] +
                         ctx_sh[2][lane] + ctx_sh[3][lane]) * inv_s;
        float v = c * fc_w[lane];
        #pragma unroll
        for (int off = 32; off > 0; off >>= 1) v += __shfl_xor(v, off, 64);
        if (lane == 0) out[b] = sigmoidf_(v + fc_b[0]);
    }
}

extern "C" void kernel_launch(void* const* d_in, const int* in_sizes, int n_in,
                              void* d_out, int out_size, void* d_ws, size_t ws_size,
                              hipStream_t stream) {
    (void)in_sizes; (void)n_in; (void)out_size; (void)ws_size;
    const float* x      = (const float*)d_in[0];
    const float* w_ih0  = (const float*)d_in[1];
    const float* w_hh0  = (const float*)d_in[2];
    const float* b_ih0  = (const float*)d_in[3];
    const float* b_hh0  = (const float*)d_in[4];
    const float* w_ih1  = (const float*)d_in[5];
    const float* w_hh1  = (const float*)d_in[6];
    const float* b_ih1  = (const float*)d_in[7];
    const float* b_hh1  = (const float*)d_in[8];
    const float* attn_w = (const float*)d_in[9];
    const float* attn_b = (const float*)d_in[10];
    const float* fc_w   = (const float*)d_in[11];
    const float* fc_b   = (const float*)d_in[12];
    float* out = (float*)d_out;

    float* h1   = (float*)d_ws;                       // 128 MiB
    float* out2 = h1 + (size_t)BB * TT * 64;          // 128 MiB

    gru_l0<<<BB*2, 64, 0, stream>>>(x, w_ih0, w_hh0, b_ih0, b_hh0, h1);
    gru_l1<<<BB*2, 64, 0, stream>>>(h1, w_ih1, w_hh1, b_ih1, b_hh1, out2);
    attn_fc<<<BB, 256, 0, stream>>>(out2, attn_w, attn_b, fc_w, fc_b, out);
}

// Round 7
// 889.418 us; speedup vs baseline: 1.0495x; 1.0495x over previous
//
#include <hip/hip_runtime.h>
#include <math.h>

#define BB 1024
#define TT 512

__device__ __forceinline__ float fast_rcp(float x){ return __builtin_amdgcn_rcpf(x); }
__device__ __forceinline__ float sigmoidf_(float x){ return fast_rcp(1.0f + __expf(-x)); }
__device__ __forceinline__ float tanhf_(float x){
    float t = __expf(2.0f * x);
    return 1.0f - 2.0f * fast_rcp(t + 1.0f);
}

// Layer 0 bidirectional GRU. Block = 1 wave = one (batch, direction) sequence.
// lane = i + 32*half: i = h-element, half = k-split half of the recurrent dot.
// __launch_bounds__(64,1): min-waves=1 releases the compiler's VGPR cap to 256
// so the ~90-reg weight set stays register-resident (min-waves=2 capped at
// ~128 and rematerialized the invariant weight loads inside the t-loop —
// R4/R5/R6 all showed VGPR ~100 and in-loop reloads). HW still co-schedules
// 2 waves/SIMD at this register count (waves halve at vgpr={64,128,256}).
__global__ __launch_bounds__(64, 1) void gru_l0(
    const float* __restrict__ x,      // (B,T,4)
    const float* __restrict__ w_ih,   // (2,96,4)
    const float* __restrict__ w_hh,   // (2,96,32)
    const float* __restrict__ b_ih,   // (2,96)
    const float* __restrict__ b_hh,   // (2,96)
    float* __restrict__ h1)           // (B,T,64)
{
    const int b    = blockIdx.x >> 1;
    const int d    = blockIdx.x & 1;
    const int lane = threadIdx.x;
    const int i    = lane & 31;
    const int half = lane >> 5;

    float4 wi[3];        // full input row (4), redundant across halves
    float4 wh[3][4];     // recurrent row, j-range [half*16, half*16+16)
    float  bx[3];        // g=0,1: b_ih+b_hh ; g=2: b_ih only
    float  bhn;          // b_hh for n gate (stays inside r*(...))
    #pragma unroll
    for (int g = 0; g < 3; ++g) {
        const int row = d*96 + g*32 + i;
        wi[g] = *(const float4*)(w_ih + (size_t)row*4);
        #pragma unroll
        for (int k = 0; k < 4; ++k)
            wh[g][k] = *(const float4*)(w_hh + (size_t)row*32 + half*16 + k*4);
        bx[g] = (g < 2) ? (b_ih[row] + b_hh[row]) : b_ih[row];
    }
    bhn = b_hh[d*96 + 2*32 + i];

    __shared__ __align__(16) float h_sh[32];
    if (!half) h_sh[i] = 0.0f;
    float h = 0.0f;

    const size_t xbase = (size_t)b * TT;
    float4 xc = *(const float4*)(x + (xbase + (d ? TT-1 : 0))*4);

    for (int t = 0; t < TT; ++t) {
        const int tx = d ? (TT-1-t) : t;
        float4 xn4 = xc;
        if (t+1 < TT) {
            const int tx1 = d ? (TT-2-t) : (t+1);
            xn4 = *(const float4*)(x + (xbase + tx1)*4);
        }
        float xg[3], hg[3];
        #pragma unroll
        for (int g = 0; g < 3; ++g) {
            xg[g] = bx[g] + xc.x*wi[g].x + xc.y*wi[g].y + xc.z*wi[g].z + xc.w*wi[g].w;
            hg[g] = 0.0f;
        }
        #pragma unroll
        for (int k = 0; k < 4; ++k) {
            const float4 hv = *(const float4*)&h_sh[half*16 + k*4];  // per-half broadcast
            #pragma unroll
            for (int g = 0; g < 3; ++g)
                hg[g] += hv.x*wh[g][k].x + hv.y*wh[g][k].y + hv.z*wh[g][k].z + hv.w*wh[g][k].w;
        }
        #pragma unroll
        for (int g = 0; g < 3; ++g) hg[g] += __shfl_xor(hg[g], 32, 64);
        const float r = sigmoidf_(xg[0] + hg[0]);
        const float z = sigmoidf_(xg[1] + hg[1]);
        const float n = tanhf_(xg[2] + r*(hg[2] + bhn));
        h = n + z*(h - n);
        if (!half) {
            h_sh[i] = h;
            h1[(xbase + tx)*64 + d*32 + i] = h;
        }
        xc = xn4;
    }
}

// Layer 1 bidirectional GRU, input width 64. Same wave layout; projection
// k-split too (wi: 96 VGPR, wh: 48 VGPR -> ~190 live incl. working set,
// fits the 256 cap that launch_bounds(64,1) releases).
__global__ __launch_bounds__(64, 1) void gru_l1(
    const float* __restrict__ h1,     // (B,T,64)
    const float* __restrict__ w_ih,   // (2,96,64)
    const float* __restrict__ w_hh,   // (2,96,32)
    const float* __restrict__ b_ih,   // (2,96)
    const float* __restrict__ b_hh,   // (2,96)
    float* __restrict__ out2)         // (B,T,64)
{
    const int b    = blockIdx.x >> 1;
    const int d    = blockIdx.x & 1;
    const int lane = threadIdx.x;
    const int i    = lane & 31;
    const int half = lane >> 5;

    float4 wi[3][8];     // proj row, k-range [half*32, half*32+32)
    float4 wh[3][4];     // rec row, j-range [half*16, half*16+16)
    float  bx[3];
    float  bhn;
    #pragma unroll
    for (int g = 0; g < 3; ++g) {
        const size_t row = (size_t)(d*96 + g*32 + i);
        #pragma unroll
        for (int k = 0; k < 8; ++k)
            wi[g][k] = *(const float4*)(w_ih + row*64 + half*32 + k*4);
        #pragma unroll
        for (int k = 0; k < 4; ++k)
            wh[g][k] = *(const float4*)(w_hh + row*32 + half*16 + k*4);
        bx[g] = (g < 2) ? (b_ih[row] + b_hh[row]) : b_ih[row];
    }
    bhn = b_hh[d*96 + 2*32 + i];

    __shared__ __align__(16) float h_sh[32];
    __shared__ __align__(16) float xbuf[2][64];
    if (!half) h_sh[i] = 0.0f;
    float h = 0.0f;

    const size_t base = (size_t)b * TT;

    // stage row 0; prefetch row 1 (1 float per lane, coalesced 256B)
    float c1;
    {
        const int r0 = d ? (TT-1) : 0;
        xbuf[0][lane] = h1[(base + r0)*64 + lane];
        const int r1 = d ? (TT-2) : 1;
        c1 = h1[(base + r1)*64 + lane];
    }

    int buf = 0;
    for (int t = 0; t < TT; ++t) {
        // prefetch row t+2 (2 steps of latency cover)
        float c2 = c1;
        if (t+2 < TT) {
            const int r2 = d ? (TT-3-t) : (t+2);
            c2 = h1[(base + r2)*64 + lane];
        }
        // projection from staged row (independent of h -> hides h LDS round trip)
        float xg[3], hg[3];
        #pragma unroll
        for (int g = 0; g < 3; ++g) { xg[g] = bx[g]; hg[g] = 0.0f; }
        #pragma unroll
        for (int k = 0; k < 8; ++k) {
            const float4 xv = *(const float4*)&xbuf[buf][half*32 + k*4];  // broadcast
            #pragma unroll
            for (int g = 0; g < 3; ++g)
                xg[g] += xv.x*wi[g][k].x + xv.y*wi[g][k].y + xv.z*wi[g][k].z + xv.w*wi[g][k].w;
        }
        // stage row t+1 into the other buffer (c1 ready from last iter's prefetch)
        if (t+1 < TT) xbuf[buf^1][lane] = c1;
        // recurrent part
        #pragma unroll
        for (int k = 0; k < 4; ++k) {
            const float4 hv = *(const float4*)&h_sh[half*16 + k*4];       // broadcast
            #pragma unroll
            for (int g = 0; g < 3; ++g)
                hg[g] += hv.x*wh[g][k].x + hv.y*wh[g][k].y + hv.z*wh[g][k].z + hv.w*wh[g][k].w;
        }
        #pragma unroll
        for (int g = 0; g < 3; ++g) hg[g] += __shfl_xor(hg[g], 32, 64);
        const float r = sigmoidf_(xg[0] + hg[0]);
        const float z = sigmoidf_(xg[1] + hg[1]);
        const float n = tanhf_(xg[2] + r*(hg[2] + bhn));
        h = n + z*(h - n);
        if (!half) {
            h_sh[i] = h;
            const int tx = d ? (TT-1-t) : t;
            out2[(base + tx)*64 + d*32 + i] = h;
        }
        c1 = c2;
        buf ^= 1;
    }
}

// Attention pooling + FC + sigmoid. One block per batch element.
__global__ __launch_bounds__(256) void attn_fc(
    const float* __restrict__ out2,   // (B,T,64)
    const float* __restrict__ attn_w, // (64)
    const float* __restrict__ attn_b, // (1)
    const float* __restrict__ fc_w,   // (64)
    const float* __restrict__ fc_b,   // (1)
    float* __restrict__ out)          // (B,1)
{
    const int b    = blockIdx.x;
    const int tid  = threadIdx.x;
    const int wave = tid >> 6;
    const int lane = tid & 63;

    __shared__ float logit_sh[TT];
    __shared__ float red_sh[4];
    __shared__ float ctx_sh[4][64];

    const float aw = attn_w[lane];
    const float ab = attn_b[0];

    for (int t = wave; t < TT; t += 4) {
        float v = out2[((size_t)b*TT + t)*64 + lane] * aw;
        #pragma unroll
        for (int off = 32; off > 0; off >>= 1) v += __shfl_xor(v, off, 64);
        if (lane == 0) logit_sh[t] = v + ab;
    }
    __syncthreads();

    float m = -INFINITY;
    for (int t = tid; t < TT; t += 256) m = fmaxf(m, logit_sh[t]);
    #pragma unroll
    for (int off = 32; off > 0; off >>= 1) m = fmaxf(m, __shfl_xor(m, off, 64));
    if (lane == 0) red_sh[wave] = m;
    __syncthreads();
    m = fmaxf(fmaxf(red_sh[0], red_sh[1]), fmaxf(red_sh[2], red_sh[3]));
    __syncthreads();
    float s = 0.0f;
    for (int t = tid; t < TT; t += 256) {
        const float e = __expf(logit_sh[t] - m);
        logit_sh[t] = e;
        s += e;
    }
    #pragma unroll
    for (int off = 32; off > 0; off >>= 1) s += __shfl_xor(s, off, 64);
    if (lane == 0) red_sh[wave] = s;
    __syncthreads();
    s = red_sh[0] + red_sh[1] + red_sh[2] + red_sh[3];
    const float inv_s = 1.0f / s;

    float acc = 0.0f;
    for (int t = wave; t < TT; t += 4)
        acc += logit_sh[t] * out2[((size_t)b*TT + t)*64 + lane];
    ctx_sh[wave][lane] = acc;
    __syncthreads();
    if (wave == 0) {
        const float c = (ctx_sh[0][lane] + ctx_sh[1][lane] +
                         ctx_sh[2][lane] + ctx_sh[3][lane]) * inv_s;
        float v = c * fc_w[lane];
        #pragma unroll
        for (int off = 32; off > 0; off >>= 1) v += __shfl_xor(v, off, 64);
        if (lane == 0) out[b] = sigmoidf_(v + fc_b[0]);
    }
}

extern "C" void kernel_launch(void* const* d_in, const int* in_sizes, int n_in,
                              void* d_out, int out_size, void* d_ws, size_t ws_size,
                              hipStream_t stream) {
    (void)in_sizes; (void)n_in; (void)out_size; (void)ws_size;
    const float* x      = (const float*)d_in[0];
    const float* w_ih0  = (const float*)d_in[1];
    const float* w_hh0  = (const float*)d_in[2];
    const float* b_ih0  = (const float*)d_in[3];
    const float* b_hh0  = (const float*)d_in[4];
    const float* w_ih1  = (const float*)d_in[5];
    const float* w_hh1  = (const float*)d_in[6];
    const float* b_ih1  = (const float*)d_in[7];
    const float* b_hh1  = (const float*)d_in[8];
    const float* attn_w = (const float*)d_in[9];
    const float* attn_b = (const float*)d_in[10];
    const float* fc_w   = (const float*)d_in[11];
    const float* fc_b   = (const float*)d_in[12];
    float* out = (float*)d_out;

    float* h1   = (float*)d_ws;                       // 128 MiB
    float* out2 = h1 + (size_t)BB * TT * 64;          // 128 MiB

    gru_l0<<<BB*2, 64, 0, stream>>>(x, w_ih0, w_hh0, b_ih0, b_hh0, h1);
    gru_l1<<<BB*2, 64, 0, stream>>>(h1, w_ih1, w_hh1, b_ih1, b_hh1, out2);
    attn_fc<<<BB, 256, 0, stream>>>(out2, attn_w, attn_b, fc_w, fc_b, out);
}